// Round 1
// baseline (1941.228 us; speedup 1.0000x reference)
//
#include <hip/hip_runtime.h>

typedef __attribute__((ext_vector_type(8))) short s16x8;
typedef __attribute__((ext_vector_type(4))) float f32x4;
typedef __attribute__((ext_vector_type(4))) int i32x4;

#define NMID 782
#define PI_2 1.5707963267948966f
#define AT_HALF_ELEMS (NMID * 64 * 128)  // bf16 elements per half (hi or lo)

__device__ __forceinline__ int cvt_pk_bf16(float lo, float hi) {
  int r;
  asm("v_cvt_pk_bf16_f32 %0, %1, %2" : "=v"(r) : "v"(lo), "v"(hi));
  return r;
}

__device__ __forceinline__ f32x4 mfma_bf16(i32x4 a, i32x4 b, f32x4 c) {
  return __builtin_amdgcn_mfma_f32_16x16x32_bf16(
      __builtin_bit_cast(s16x8, a), __builtin_bit_cast(s16x8, b), c, 0, 0, 0);
}

// ---- preprocessing: cores_mid [782][2][64][64] f32 -> AThi/ATlo [782][64][128] bf16
// AT[n][j][k] = hi/lo(cores_mid[n][f][i][j]), k = f*64 + i  (transposed, f-stacked)
__global__ __launch_bounds__(256) void prep_at(const float* __restrict__ cm,
                                               unsigned short* __restrict__ athi,
                                               unsigned short* __restrict__ atlo) {
  __shared__ float tile[2 * 64 * 65];
  const int n = blockIdx.x;
  const float* src = cm + (size_t)n * 8192;
#pragma unroll
  for (int e = 0; e < 32; ++e) {
    int idx = e * 256 + threadIdx.x;  // [f][i][j]
    int fi = idx >> 6, j = idx & 63;
    tile[fi * 65 + j] = src[idx];
  }
  __syncthreads();
  unsigned short* dh = athi + (size_t)n * 8192;
  unsigned short* dl = atlo + (size_t)n * 8192;
#pragma unroll
  for (int e = 0; e < 32; ++e) {
    int idx = e * 256 + threadIdx.x;  // j*128 + k
    int j = idx >> 7, k = idx & 127;
    float v = tile[k * 65 + j];  // k = f*64+i == fi
    unsigned u = __float_as_uint(v);
    unsigned hb = (u + 0x7FFFu + ((u >> 16) & 1)) & 0xFFFF0000u;  // RNE-ish
    float lo = v - __uint_as_float(hb);
    unsigned ul = __float_as_uint(lo);
    unsigned lb = (ul + 0x7FFFu + ((ul >> 16) & 1));
    dh[idx] = (unsigned short)(hb >> 16);
    dl[idx] = (unsigned short)(lb >> 16);
  }
}

// ---- main: 512 blocks x 64 threads; each 1-wave WG owns 16 batch rows.
// Master M in C'-layout: lane (bl = lane&15 -> row b, h = lane>>4) holds
// m[t*4+r] = M[b][j], j = 16t + 4h + r.
__global__ __launch_bounds__(64) void mps_main(
    const float* __restrict__ x, const float* __restrict__ core0,
    const float* __restrict__ core_last,
    const unsigned short* __restrict__ athi, const unsigned short* __restrict__ atlo,
    float* __restrict__ out) {
  __shared__ float sc[16 * 76];  // padded stride 76 -> conflict-free b128 r/w
  const int lane = threadIdx.x;
  const int bl = lane & 15;
  const int h = lane >> 4;
  const int b = blockIdx.x * 16 + bl;

  float m[16];
  {
    float xv = x[(size_t)b * 784];
    float s, c;
    __sincosf(PI_2 * xv, &s, &c);
#pragma unroll
    for (int t = 0; t < 4; ++t)
#pragma unroll
      for (int r = 0; r < 4; ++r) {
        int j = 16 * t + 4 * h + r;
        m[t * 4 + r] = c * core0[j] + s * core0[64 + j];
      }
  }

  const char* pbh = (const char*)athi + (size_t)bl * 256 + (size_t)h * 16;
  const char* pbl = (const char*)atlo + (size_t)bl * 256 + (size_t)h * 16;

  for (int n = 0; n < NMID; ++n) {
    float xv = x[(size_t)b * 784 + n + 1];
    float s, c;
    __sincosf(PI_2 * xv, &s, &c);

    // permute M (C'-layout j-slices) -> B-frag i-runs via per-wave LDS scratch
#pragma unroll
    for (int t = 0; t < 4; ++t)
      *(f32x4*)&sc[bl * 76 + 16 * t + 4 * h] = *(f32x4*)&m[4 * t];
    __syncthreads();
    float om[16];  // om[0..7] = M[b][8h..8h+7], om[8..15] = M[b][32+8h..]
    *(f32x4*)&om[0] = *(const f32x4*)&sc[bl * 76 + 8 * h];
    *(f32x4*)&om[4] = *(const f32x4*)&sc[bl * 76 + 8 * h + 4];
    *(f32x4*)&om[8] = *(const f32x4*)&sc[bl * 76 + 32 + 8 * h];
    *(f32x4*)&om[12] = *(const f32x4*)&sc[bl * 76 + 32 + 8 * h + 4];
    __syncthreads();

    // B-frags: chunk cc covers k=32cc+8h+e; cc 0,1 -> f=0 (*cos), cc 2,3 -> f=1 (*sin)
    i32x4 bh[4], blo[4];
#pragma unroll
    for (int cc = 0; cc < 4; ++cc) {
      float vf = (cc < 2) ? c : s;
      int base = (cc & 1) * 8;
      int hp[4], lp[4];
#pragma unroll
      for (int p = 0; p < 4; ++p) {
        float f0 = vf * om[base + 2 * p];
        float f1 = vf * om[base + 2 * p + 1];
        int hh = cvt_pk_bf16(f0, f1);
        float h0 = __uint_as_float(((unsigned)hh) << 16);
        float h1 = __uint_as_float(((unsigned)hh) & 0xFFFF0000u);
        int ll = cvt_pk_bf16(f0 - h0, f1 - h1);
        hp[p] = hh;
        lp[p] = ll;
      }
      bh[cc] = (i32x4){hp[0], hp[1], hp[2], hp[3]};
      blo[cc] = (i32x4){lp[0], lp[1], lp[2], lp[3]};
    }

    const char* pan = pbh + (size_t)n * 16384;
    const char* pln = pbl + (size_t)n * 16384;
#pragma unroll
    for (int t = 0; t < 4; ++t) {
      i32x4 ah[4], al[4];
#pragma unroll
      for (int cc = 0; cc < 4; ++cc) {
        ah[cc] = *(const i32x4*)(pan + t * 4096 + cc * 64);
        al[cc] = *(const i32x4*)(pln + t * 4096 + cc * 64);
      }
      f32x4 accA = {0.f, 0.f, 0.f, 0.f}, accB = {0.f, 0.f, 0.f, 0.f};
      accA = mfma_bf16(ah[0], bh[0], accA);
      accB = mfma_bf16(ah[1], bh[1], accB);
      accA = mfma_bf16(ah[2], bh[2], accA);
      accB = mfma_bf16(ah[3], bh[3], accB);
      accA = mfma_bf16(al[0], bh[0], accA);
      accB = mfma_bf16(al[1], bh[1], accB);
      accA = mfma_bf16(al[2], bh[2], accA);
      accB = mfma_bf16(al[3], bh[3], accB);
      accA = mfma_bf16(ah[0], blo[0], accA);
      accB = mfma_bf16(ah[1], blo[1], accB);
      accA = mfma_bf16(ah[2], blo[2], accA);
      accB = mfma_bf16(ah[3], blo[3], accB);
      f32x4 acc = accA + accB;
#pragma unroll
      for (int r = 0; r < 4; ++r) m[4 * t + r] = acc[r];
    }

    if ((n & 63) == 63) {  // periodic rescale (direction-invariant)
      float ss = 0.f;
#pragma unroll
      for (int i = 0; i < 16; ++i) ss += m[i] * m[i];
      ss += __shfl_xor(ss, 16);
      ss += __shfl_xor(ss, 32);
      float inv = rsqrtf(ss);
#pragma unroll
      for (int i = 0; i < 16; ++i) m[i] *= inv;
    }
  }

  // final normalize (matches ref: every-step norms cancel in direction)
  float ss = 0.f;
#pragma unroll
  for (int i = 0; i < 16; ++i) ss += m[i] * m[i];
  ss += __shfl_xor(ss, 16);
  ss += __shfl_xor(ss, 32);
  float inv = 1.0f / (sqrtf(ss) + 1e-8f);
#pragma unroll
  for (int i = 0; i < 16; ++i) m[i] *= inv;

  float xv = x[(size_t)b * 784 + 783];
  float s, c;
  __sincosf(PI_2 * xv, &s, &c);
  float part[10];
#pragma unroll
  for (int cc = 0; cc < 10; ++cc) part[cc] = 0.f;
#pragma unroll
  for (int t = 0; t < 4; ++t)
#pragma unroll
    for (int r = 0; r < 4; ++r) {
      int i = 16 * t + 4 * h + r;
      float mv = m[4 * t + r];
#pragma unroll
      for (int cc = 0; cc < 10; ++cc)
        part[cc] += mv * (c * core_last[i * 10 + cc] + s * core_last[640 + i * 10 + cc]);
    }
#pragma unroll
  for (int cc = 0; cc < 10; ++cc) {
    part[cc] += __shfl_xor(part[cc], 16);
    part[cc] += __shfl_xor(part[cc], 32);
  }
  if (h == 0) {
#pragma unroll
    for (int cc = 0; cc < 10; ++cc) out[b * 10 + cc] = part[cc];
  }
}

// ---- fallback (only if d_ws too small): slow but exact-structured scalar path
__global__ __launch_bounds__(64) void mps_slow(const float* __restrict__ x,
                                               const float* __restrict__ core0,
                                               const float* __restrict__ cm,
                                               const float* __restrict__ cl,
                                               float* __restrict__ out) {
  int b = blockIdx.x * 64 + threadIdx.x;
  float m[64], mn[64];
  float s, c;
  __sincosf(PI_2 * x[(size_t)b * 784], &s, &c);
  for (int d = 0; d < 64; ++d) m[d] = c * core0[d] + s * core0[64 + d];
  for (int n = 0; n < NMID; ++n) {
    __sincosf(PI_2 * x[(size_t)b * 784 + n + 1], &s, &c);
    const float* A0 = cm + (size_t)n * 8192;
    const float* A1 = A0 + 4096;
    for (int j = 0; j < 64; ++j) mn[j] = 0.f;
    for (int i = 0; i < 64; ++i) {
      float w0 = c * m[i], w1 = s * m[i];
      for (int j = 0; j < 64; ++j) mn[j] += w0 * A0[i * 64 + j] + w1 * A1[i * 64 + j];
    }
    float ss = 0.f;
    for (int j = 0; j < 64; ++j) ss += mn[j] * mn[j];
    float inv = 1.f / (sqrtf(ss) + 1e-8f);
    for (int j = 0; j < 64; ++j) m[j] = mn[j] * inv;
  }
  __sincosf(PI_2 * x[(size_t)b * 784 + 783], &s, &c);
  for (int cc = 0; cc < 10; ++cc) {
    float acc = 0.f;
    for (int i = 0; i < 64; ++i)
      acc += m[i] * (c * cl[i * 10 + cc] + s * cl[640 + i * 10 + cc]);
    out[b * 10 + cc] = acc;
  }
}

extern "C" void kernel_launch(void* const* d_in, const int* in_sizes, int n_in,
                              void* d_out, int out_size, void* d_ws, size_t ws_size,
                              hipStream_t stream) {
  const float* x = (const float*)d_in[0];
  const float* core0 = (const float*)d_in[1];
  const float* cm = (const float*)d_in[2];
  const float* cl = (const float*)d_in[3];
  float* out = (float*)d_out;
  size_t need = (size_t)2 * AT_HALF_ELEMS * sizeof(unsigned short);
  if (ws_size >= need) {
    unsigned short* athi = (unsigned short*)d_ws;
    unsigned short* atlo = athi + AT_HALF_ELEMS;
    prep_at<<<NMID, 256, 0, stream>>>(cm, athi, atlo);
    mps_main<<<512, 64, 0, stream>>>(x, core0, cl, athi, atlo, out);
  } else {
    mps_slow<<<8192 / 64, 64, 0, stream>>>(x, core0, cm, cl, out);
  }
}

// Round 2
// 447.756 us; speedup vs baseline: 4.3355x; 4.3355x over previous
//
#include <hip/hip_runtime.h>

typedef __attribute__((ext_vector_type(8))) short s16x8;
typedef __attribute__((ext_vector_type(4))) float f32x4;
typedef __attribute__((ext_vector_type(4))) int i32x4;

#define NMID 782
#define PI_2 1.5707963267948966f
#define EG_STEP_BYTES 16384  // [16 frag][64 lane][16B]
#define EG_ELEMS ((size_t)NMID * 8192)

__device__ __forceinline__ int cvt_pk_bf16(float a, float b) {
  int r;
  asm("v_cvt_pk_bf16_f32 %0, %1, %2" : "=v"(r) : "v"(a), "v"(b));
  return r;
}

__device__ __forceinline__ f32x4 mfma_bf16(i32x4 a, i32x4 b, f32x4 c) {
  return __builtin_amdgcn_mfma_f32_16x16x32_bf16(
      __builtin_bit_cast(s16x8, a), __builtin_bit_cast(s16x8, b), c, 0, 0, 0);
}

__device__ __forceinline__ unsigned short bf16_rne(float v) {
  unsigned u = __float_as_uint(v);
  return (unsigned short)((u + 0x7FFFu + ((u >> 16) & 1)) >> 16);
}

// ---- prep: cm [782][2][64][64] f32 -> EG [782][16][64][8] bf16, E = cm - I,
// rows permuted by pi and laid out fragment-linear for direct b128 loads.
// EG[n][q=t*4+cc][l][e] = cm[n][f][i][j] - (i==j), where f=cc>>1, h=l>>4,
//   i = 32*(cc&1) + 16*(e>>2) + 4*h + (e&3),  j = 16*t + (l&15).
__global__ __launch_bounds__(256) void prep_eg(const float* __restrict__ cm,
                                               unsigned short* __restrict__ eg) {
  const int n = blockIdx.x;
  const float* src = cm + (size_t)n * 8192;
  unsigned short* dst = eg + (size_t)n * 8192;
#pragma unroll
  for (int it = 0; it < 4; ++it) {
    int row = it * 256 + threadIdx.x;  // [0,1024): (t*4+cc)*64 + l
    int q = row >> 6, l = row & 63;
    int t = q >> 2, cc = q & 3;
    int f = cc >> 1, c2 = cc & 1, h = l >> 4;
    int j = 16 * t + (l & 15);
    unsigned short v8[8];
#pragma unroll
    for (int e = 0; e < 8; ++e) {
      int i = 32 * c2 + 16 * (e >> 2) + 4 * h + (e & 3);
      float val = src[(f * 64 + i) * 64 + j] - (i == j ? 1.0f : 0.0f);
      v8[e] = bf16_rne(val);
    }
    *(uint4*)(dst + (size_t)row * 8) = *(const uint4*)v8;
  }
}

// One chain step: consume fragments CUR (step nc), prefetch step np into NXT.
#define STEP(nc, CUR, NXT)                                                   \
  {                                                                          \
    int np = (nc) + 1;                                                       \
    if (np >= NMID) np = NMID - 1;                                           \
    const char* pnxt = base + (size_t)np * EG_STEP_BYTES;                    \
    _Pragma("unroll") for (int q = 0; q < 16; ++q)                           \
        NXT[q] = *(const i32x4*)(pnxt + q * 1024);                           \
    float xv = x[(size_t)b * 784 + (nc) + 1];                                \
    float s, c;                                                              \
    __sincosf(PI_2 * xv, &s, &c);                                            \
    if (((nc)&63) == 0) { /* periodic rescale: direction-invariant */        \
      float ss = 0.f;                                                        \
      _Pragma("unroll") for (int i = 0; i < 16; ++i) ss += m[i] * m[i];      \
      ss += __shfl_xor(ss, 16);                                              \
      ss += __shfl_xor(ss, 32);                                              \
      float inv = rsqrtf(ss);                                                \
      _Pragma("unroll") for (int i = 0; i < 16; ++i) m[i] *= inv;            \
    }                                                                        \
    int b0[4], b1[4];                                                        \
    _Pragma("unroll") for (int p = 0; p < 4; ++p) {                          \
      b0[p] = cvt_pk_bf16(m[2 * p], m[2 * p + 1]);                           \
      b1[p] = cvt_pk_bf16(m[8 + 2 * p], m[8 + 2 * p + 1]);                   \
    }                                                                        \
    i32x4 B0 = {b0[0], b0[1], b0[2], b0[3]};                                 \
    i32x4 B1 = {b1[0], b1[1], b1[2], b1[3]};                                 \
    float cps = c + s;                                                       \
    _Pragma("unroll") for (int t = 0; t < 4; ++t) {                          \
      f32x4 z = {0.f, 0.f, 0.f, 0.f};                                        \
      f32x4 accA = mfma_bf16(CUR[4 * t + 0], B0, z);                         \
      accA = mfma_bf16(CUR[4 * t + 1], B1, accA);                            \
      f32x4 accB = mfma_bf16(CUR[4 * t + 2], B0, z);                         \
      accB = mfma_bf16(CUR[4 * t + 3], B1, accB);                            \
      _Pragma("unroll") for (int r = 0; r < 4; ++r)                          \
          m[4 * t + r] = cps * m[4 * t + r] + c * accA[r] + s * accB[r];     \
    }                                                                        \
  }

// ---- main: 256 blocks x 128 threads (2 waves). Each wave owns 16 batch rows,
// computes all 4 t-tiles; M lives in registers the whole chain (no LDS).
__global__ __launch_bounds__(128) void mps_main(
    const float* __restrict__ x, const float* __restrict__ core0,
    const float* __restrict__ core_last, const unsigned short* __restrict__ eg,
    float* __restrict__ out) {
  const int lane = threadIdx.x & 63;
  const int wv = threadIdx.x >> 6;
  const int bl = lane & 15;
  const int h = lane >> 4;
  const int b = blockIdx.x * 32 + wv * 16 + bl;

  float m[16];
  {
    float xv = x[(size_t)b * 784];
    float s, c;
    __sincosf(PI_2 * xv, &s, &c);
#pragma unroll
    for (int t = 0; t < 4; ++t)
#pragma unroll
      for (int r = 0; r < 4; ++r) {
        int j = 16 * t + 4 * h + r;
        m[t * 4 + r] = c * core0[j] + s * core0[64 + j];
      }
  }

  const char* base = (const char*)eg + (size_t)lane * 16;

  i32x4 frA[16], frB[16];
#pragma unroll
  for (int q = 0; q < 16; ++q) frA[q] = *(const i32x4*)(base + q * 1024);

  for (int it = 0; it < NMID / 2; ++it) {
    int n0 = 2 * it;
    STEP(n0, frA, frB);
    STEP(n0 + 1, frB, frA);
  }

  // final normalize (per-step norms are direction-invariant)
  float ss = 0.f;
#pragma unroll
  for (int i = 0; i < 16; ++i) ss += m[i] * m[i];
  ss += __shfl_xor(ss, 16);
  ss += __shfl_xor(ss, 32);
  float inv = 1.0f / (sqrtf(ss) + 1e-8f);
#pragma unroll
  for (int i = 0; i < 16; ++i) m[i] *= inv;

  float xv = x[(size_t)b * 784 + 783];
  float s, c;
  __sincosf(PI_2 * xv, &s, &c);
  float part[10];
#pragma unroll
  for (int cc = 0; cc < 10; ++cc) part[cc] = 0.f;
#pragma unroll
  for (int t = 0; t < 4; ++t)
#pragma unroll
    for (int r = 0; r < 4; ++r) {
      int i = 16 * t + 4 * h + r;
      float mv = m[4 * t + r];
#pragma unroll
      for (int cc = 0; cc < 10; ++cc)
        part[cc] += mv * (c * core_last[i * 10 + cc] + s * core_last[640 + i * 10 + cc]);
    }
#pragma unroll
  for (int cc = 0; cc < 10; ++cc) {
    part[cc] += __shfl_xor(part[cc], 16);
    part[cc] += __shfl_xor(part[cc], 32);
  }
  if (h == 0) {
#pragma unroll
    for (int cc = 0; cc < 10; ++cc) out[b * 10 + cc] = part[cc];
  }
}

// ---- fallback (only if d_ws too small): slow but correct scalar path
__global__ __launch_bounds__(64) void mps_slow(const float* __restrict__ x,
                                               const float* __restrict__ core0,
                                               const float* __restrict__ cm,
                                               const float* __restrict__ cl,
                                               float* __restrict__ out) {
  int b = blockIdx.x * 64 + threadIdx.x;
  float m[64], mn[64];
  float s, c;
  __sincosf(PI_2 * x[(size_t)b * 784], &s, &c);
  for (int d = 0; d < 64; ++d) m[d] = c * core0[d] + s * core0[64 + d];
  for (int n = 0; n < NMID; ++n) {
    __sincosf(PI_2 * x[(size_t)b * 784 + n + 1], &s, &c);
    const float* A0 = cm + (size_t)n * 8192;
    const float* A1 = A0 + 4096;
    for (int j = 0; j < 64; ++j) mn[j] = 0.f;
    for (int i = 0; i < 64; ++i) {
      float w0 = c * m[i], w1 = s * m[i];
      for (int j = 0; j < 64; ++j) mn[j] += w0 * A0[i * 64 + j] + w1 * A1[i * 64 + j];
    }
    float ssn = 0.f;
    for (int j = 0; j < 64; ++j) ssn += mn[j] * mn[j];
    float inv = 1.f / (sqrtf(ssn) + 1e-8f);
    for (int j = 0; j < 64; ++j) m[j] = mn[j] * inv;
  }
  __sincosf(PI_2 * x[(size_t)b * 784 + 783], &s, &c);
  for (int cc = 0; cc < 10; ++cc) {
    float acc = 0.f;
    for (int i = 0; i < 64; ++i)
      acc += m[i] * (c * cl[i * 10 + cc] + s * cl[640 + i * 10 + cc]);
    out[b * 10 + cc] = acc;
  }
}

extern "C" void kernel_launch(void* const* d_in, const int* in_sizes, int n_in,
                              void* d_out, int out_size, void* d_ws, size_t ws_size,
                              hipStream_t stream) {
  const float* x = (const float*)d_in[0];
  const float* core0 = (const float*)d_in[1];
  const float* cm = (const float*)d_in[2];
  const float* cl = (const float*)d_in[3];
  float* out = (float*)d_out;
  size_t need = EG_ELEMS * sizeof(unsigned short);
  if (ws_size >= need) {
    unsigned short* eg = (unsigned short*)d_ws;
    prep_eg<<<NMID, 256, 0, stream>>>(cm, eg);
    mps_main<<<256, 128, 0, stream>>>(x, core0, cl, eg, out);
  } else {
    mps_slow<<<8192 / 64, 64, 0, stream>>>(x, core0, cm, cl, out);
  }
}

// Round 3
// 325.874 us; speedup vs baseline: 5.9570x; 1.3740x over previous
//
#include <hip/hip_runtime.h>

typedef __attribute__((ext_vector_type(8))) short s16x8;
typedef __attribute__((ext_vector_type(4))) float f32x4;
typedef __attribute__((ext_vector_type(4))) int i32x4;

#define NMID 782
#define PI_2 1.5707963267948966f
#define EG_STEP_BYTES 16384  // [16 frag][64 lane][16B]
#define EG_ELEMS ((size_t)NMID * 8192)

__device__ __forceinline__ int cvt_pk_bf16(float a, float b) {
  int r;
  asm("v_cvt_pk_bf16_f32 %0, %1, %2" : "=v"(r) : "v"(a), "v"(b));
  return r;
}

__device__ __forceinline__ f32x4 mfma_bf16(i32x4 a, i32x4 b, f32x4 c) {
  return __builtin_amdgcn_mfma_f32_16x16x32_bf16(
      __builtin_bit_cast(s16x8, a), __builtin_bit_cast(s16x8, b), c, 0, 0, 0);
}

__device__ __forceinline__ unsigned short bf16_rne(float v) {
  unsigned u = __float_as_uint(v);
  return (unsigned short)((u + 0x7FFFu + ((u >> 16) & 1)) >> 16);
}

// ---- prep: cm [782][2][64][64] f32 -> EG [782][16][64][8] bf16, E = cm - I,
// rows permuted by pi and laid out fragment-linear for direct b128 loads.
// EG[n][q=t*4+cc][l][e] = cm[n][f][i][j] - (i==j), where f=cc>>1, h=l>>4,
//   i = 32*(cc&1) + 16*(e>>2) + 4*h + (e&3),  j = 16*t + (l&15).
__global__ __launch_bounds__(256) void prep_eg(const float* __restrict__ cm,
                                               unsigned short* __restrict__ eg) {
  const int n = blockIdx.x;
  const float* src = cm + (size_t)n * 8192;
  unsigned short* dst = eg + (size_t)n * 8192;
#pragma unroll
  for (int it = 0; it < 4; ++it) {
    int row = it * 256 + threadIdx.x;  // [0,1024): (t*4+cc)*64 + l
    int q = row >> 6, l = row & 63;
    int t = q >> 2, cc = q & 3;
    int f = cc >> 1, c2 = cc & 1, h = l >> 4;
    int j = 16 * t + (l & 15);
    unsigned short v8[8];
#pragma unroll
    for (int e = 0; e < 8; ++e) {
      int i = 32 * c2 + 16 * (e >> 2) + 4 * h + (e & 3);
      float val = src[(f * 64 + i) * 64 + j] - (i == j ? 1.0f : 0.0f);
      v8[e] = bf16_rne(val);
    }
    *(uint4*)(dst + (size_t)row * 8) = *(const uint4*)v8;
  }
}

// One chain step: consume fragments CUR (step nc), prefetch step nc+1 -> NXT.
// No per-step x load: CC/SS come from group-batched sincos registers.
#define STEPX(nc, CUR, NXT, CC, SS)                                           \
  {                                                                           \
    int np = (nc) + 1;                                                        \
    if (np >= NMID) np = NMID - 1;                                            \
    const char* pnxt = base + (size_t)np * EG_STEP_BYTES;                     \
    _Pragma("unroll") for (int q = 0; q < 16; ++q)                            \
        NXT[q] = *(const i32x4*)(pnxt + q * 1024);                            \
    int b0[4], b1[4];                                                         \
    _Pragma("unroll") for (int p = 0; p < 4; ++p) {                           \
      b0[p] = cvt_pk_bf16(m[2 * p], m[2 * p + 1]);                            \
      b1[p] = cvt_pk_bf16(m[8 + 2 * p], m[8 + 2 * p + 1]);                    \
    }                                                                         \
    i32x4 B0 = {b0[0], b0[1], b0[2], b0[3]};                                  \
    i32x4 B1 = {b1[0], b1[1], b1[2], b1[3]};                                  \
    float cps = (CC) + (SS);                                                  \
    _Pragma("unroll") for (int t = 0; t < 4; ++t) {                           \
      f32x4 z = {0.f, 0.f, 0.f, 0.f};                                         \
      f32x4 accA = mfma_bf16(CUR[4 * t + 0], B0, z);                          \
      accA = mfma_bf16(CUR[4 * t + 1], B1, accA);                             \
      f32x4 accB = mfma_bf16(CUR[4 * t + 2], B0, z);                          \
      accB = mfma_bf16(CUR[4 * t + 3], B1, accB);                             \
      _Pragma("unroll") for (int r = 0; r < 4; ++r)                           \
          m[4 * t + r] = cps * m[4 * t + r] + (CC)*accA[r] + (SS)*accB[r];    \
    }                                                                         \
  }

// ---- main: 256 blocks x 128 threads (2 independent waves). Each wave owns
// 16 batch rows; M lives in registers the whole chain (no LDS, no barriers).
__global__ __launch_bounds__(128) void mps_main(
    const float* __restrict__ x, const float* __restrict__ core0,
    const float* __restrict__ core_last, const unsigned short* __restrict__ eg,
    float* __restrict__ out) {
  const int lane = threadIdx.x & 63;
  const int wv = threadIdx.x >> 6;
  const int bl = lane & 15;
  const int h = lane >> 4;
  const int b = blockIdx.x * 32 + wv * 16 + bl;
  const float* xr = x + (size_t)b * 784;

  float m[16];
  {
    float xv = xr[0];
    float s, c;
    __sincosf(PI_2 * xv, &s, &c);
#pragma unroll
    for (int t = 0; t < 4; ++t)
#pragma unroll
      for (int r = 0; r < 4; ++r) {
        int j = 16 * t + 4 * h + r;
        m[t * 4 + r] = c * core0[j] + s * core0[64 + j];
      }
  }

  const char* base = (const char*)eg + (size_t)lane * 16;

  // prologue: x quads for group 0 (covers x idx 1..8), fragments for step 0
  float xq[12], xqn[12];
  *(f32x4*)&xq[0] = *(const f32x4*)(xr + 0);
  *(f32x4*)&xq[4] = *(const f32x4*)(xr + 4);
  *(f32x4*)&xq[8] = *(const f32x4*)(xr + 8);

  i32x4 frA[16], frB[16];
#pragma unroll
  for (int q = 0; q < 16; ++q) frA[q] = *(const i32x4*)(base + q * 1024);

  // 97 full groups of 8 steps (n = 0..775)
  for (int g = 0; g < 97; ++g) {
    // prefetch next group's x (issued BEFORE this group's fragment loads so
    // the x wait at next group start never drains the fragment queue)
    int gn = g + 1;
    if (gn < 97) {
      *(f32x4*)&xqn[0] = *(const f32x4*)(xr + 8 * gn);
      *(f32x4*)&xqn[4] = *(const f32x4*)(xr + 8 * gn + 4);
      *(f32x4*)&xqn[8] = *(const f32x4*)(xr + 8 * gn + 8);
    } else {  // tail group: x idx 777..782 live in quads 776,780
      *(f32x4*)&xqn[0] = *(const f32x4*)(xr + 776);
      *(f32x4*)&xqn[4] = *(const f32x4*)(xr + 780);
    }

    float cg[8], sg[8];
#pragma unroll
    for (int k = 0; k < 8; ++k) __sincosf(PI_2 * xq[1 + k], &sg[k], &cg[k]);

    if ((g & 7) == 0) {  // rescale every 64 steps: direction-invariant
      float ss = 0.f;
#pragma unroll
      for (int i = 0; i < 16; ++i) ss += m[i] * m[i];
      ss += __shfl_xor(ss, 16);
      ss += __shfl_xor(ss, 32);
      float inv = rsqrtf(ss);
#pragma unroll
      for (int i = 0; i < 16; ++i) m[i] *= inv;
    }

    int n0 = 8 * g;
    STEPX(n0 + 0, frA, frB, cg[0], sg[0]);
    STEPX(n0 + 1, frB, frA, cg[1], sg[1]);
    STEPX(n0 + 2, frA, frB, cg[2], sg[2]);
    STEPX(n0 + 3, frB, frA, cg[3], sg[3]);
    STEPX(n0 + 4, frA, frB, cg[4], sg[4]);
    STEPX(n0 + 5, frB, frA, cg[5], sg[5]);
    STEPX(n0 + 6, frA, frB, cg[6], sg[6]);
    STEPX(n0 + 7, frB, frA, cg[7], sg[7]);

#pragma unroll
    for (int i = 0; i < 12; ++i) xq[i] = xqn[i];
  }

  // tail: 6 steps, n = 776..781; xq[0..7] = x[776..783]
  {
    float cg[6], sg[6];
#pragma unroll
    for (int k = 0; k < 6; ++k) __sincosf(PI_2 * xq[1 + k], &sg[k], &cg[k]);
    STEPX(776, frA, frB, cg[0], sg[0]);
    STEPX(777, frB, frA, cg[1], sg[1]);
    STEPX(778, frA, frB, cg[2], sg[2]);
    STEPX(779, frB, frA, cg[3], sg[3]);
    STEPX(780, frA, frB, cg[4], sg[4]);
    STEPX(781, frB, frA, cg[5], sg[5]);
  }

  // final normalize (per-step norms are direction-invariant)
  float ss = 0.f;
#pragma unroll
  for (int i = 0; i < 16; ++i) ss += m[i] * m[i];
  ss += __shfl_xor(ss, 16);
  ss += __shfl_xor(ss, 32);
  float inv = 1.0f / (sqrtf(ss) + 1e-8f);
#pragma unroll
  for (int i = 0; i < 16; ++i) m[i] *= inv;

  float xv = xr[783];
  float s, c;
  __sincosf(PI_2 * xv, &s, &c);
  float part[10];
#pragma unroll
  for (int cc = 0; cc < 10; ++cc) part[cc] = 0.f;
#pragma unroll
  for (int t = 0; t < 4; ++t)
#pragma unroll
    for (int r = 0; r < 4; ++r) {
      int i = 16 * t + 4 * h + r;
      float mv = m[4 * t + r];
#pragma unroll
      for (int cc = 0; cc < 10; ++cc)
        part[cc] += mv * (c * core_last[i * 10 + cc] + s * core_last[640 + i * 10 + cc]);
    }
#pragma unroll
  for (int cc = 0; cc < 10; ++cc) {
    part[cc] += __shfl_xor(part[cc], 16);
    part[cc] += __shfl_xor(part[cc], 32);
  }
  if (h == 0) {
#pragma unroll
    for (int cc = 0; cc < 10; ++cc) out[b * 10 + cc] = part[cc];
  }
}

// ---- fallback (only if d_ws too small): slow but correct scalar path
__global__ __launch_bounds__(64) void mps_slow(const float* __restrict__ x,
                                               const float* __restrict__ core0,
                                               const float* __restrict__ cm,
                                               const float* __restrict__ cl,
                                               float* __restrict__ out) {
  int b = blockIdx.x * 64 + threadIdx.x;
  float m[64], mn[64];
  float s, c;
  __sincosf(PI_2 * x[(size_t)b * 784], &s, &c);
  for (int d = 0; d < 64; ++d) m[d] = c * core0[d] + s * core0[64 + d];
  for (int n = 0; n < NMID; ++n) {
    __sincosf(PI_2 * x[(size_t)b * 784 + n + 1], &s, &c);
    const float* A0 = cm + (size_t)n * 8192;
    const float* A1 = A0 + 4096;
    for (int j = 0; j < 64; ++j) mn[j] = 0.f;
    for (int i = 0; i < 64; ++i) {
      float w0 = c * m[i], w1 = s * m[i];
      for (int j = 0; j < 64; ++j) mn[j] += w0 * A0[i * 64 + j] + w1 * A1[i * 64 + j];
    }
    float ssn = 0.f;
    for (int j = 0; j < 64; ++j) ssn += mn[j] * mn[j];
    float inv = 1.f / (sqrtf(ssn) + 1e-8f);
    for (int j = 0; j < 64; ++j) m[j] = mn[j] * inv;
  }
  __sincosf(PI_2 * x[(size_t)b * 784 + 783], &s, &c);
  for (int cc = 0; cc < 10; ++cc) {
    float acc = 0.f;
    for (int i = 0; i < 64; ++i)
      acc += m[i] * (c * cl[i * 10 + cc] + s * cl[640 + i * 10 + cc]);
    out[b * 10 + cc] = acc;
  }
}

extern "C" void kernel_launch(void* const* d_in, const int* in_sizes, int n_in,
                              void* d_out, int out_size, void* d_ws, size_t ws_size,
                              hipStream_t stream) {
  const float* x = (const float*)d_in[0];
  const float* core0 = (const float*)d_in[1];
  const float* cm = (const float*)d_in[2];
  const float* cl = (const float*)d_in[3];
  float* out = (float*)d_out;
  size_t need = EG_ELEMS * sizeof(unsigned short);
  if (ws_size >= need) {
    unsigned short* eg = (unsigned short*)d_ws;
    prep_eg<<<NMID, 256, 0, stream>>>(cm, eg);
    mps_main<<<256, 128, 0, stream>>>(x, core0, cl, eg, out);
  } else {
    mps_slow<<<8192 / 64, 64, 0, stream>>>(x, core0, cm, cl, out);
  }
}